// Round 3
// baseline (660.334 us; speedup 1.0000x reference)
//
#include <hip/hip_runtime.h>

#define S_LEN 2048
#define D_DIM 1024

// ============================ Phase 1 ============================
// Fused GEMM: [32 tok x 1024] x [1024 x 140(pad 160)] -> feats/sel/comb,
// then per-token epilogue: softmax(sel)->probs, C=sum_m p_m T_m, t=C@feat.
// v2: weights staged in LDS (coalesced float4), reg-staged prefetch (T14).
#define P1_KC 32
#define P1_XSTR 36     // 32 tokens + pad
#define P1_OSTR 164    // 160 cols + pad 4

__global__ __launch_bounds__(256) void lap_phase1(
    const float* __restrict__ x,
    const float* __restrict__ gen_w, const float* __restrict__ gen_b,
    const float* __restrict__ sel_w, const float* __restrict__ sel_b,
    const float* __restrict__ templates,
    const float* __restrict__ comb_w, const float* __restrict__ comb_b,
    float* __restrict__ kf, float* __restrict__ tv, float* __restrict__ combo)
{
    __shared__ float xs[P1_KC][P1_XSTR];     // [k][tok]
    __shared__ float wlds[P1_KC][P1_OSTR];   // [k][col]
    __shared__ float outs[32][P1_OSTR];

    const int tid = threadIdx.x;
    const int tok0 = blockIdx.x * 32;
    const int cg = tid & 31;   // col group: cols cg*5..+5
    const int tg = tid >> 5;   // tok group: toks tg*4..+4

    // bias folded into acc init
    float bias5[5];
#pragma unroll
    for (int cc = 0; cc < 5; ++cc) {
        int col = cg * 5 + cc;
        if (col < 128)      bias5[cc] = gen_b[col];
        else if (col < 136) bias5[cc] = sel_b[col-128];
        else if (col < 140) bias5[cc] = comb_b[col-136];
        else                bias5[cc] = 0.0f;
    }
    float acc[4][5];
#pragma unroll
    for (int r = 0; r < 4; ++r)
#pragma unroll
        for (int cc = 0; cc < 5; ++cc) acc[r][cc] = bias5[cc];

    // staging mapping
    const int sx_tok = tid >> 3;   // 0..31
    const int sx_kq  = tid & 7;    // 0..7  (k-quad)
    float4 xr;       // x prefetch reg
    float4 wr[5];    // weight prefetch regs

    auto load_step = [&](int k0) {
        xr = *(const float4*)(x + (size_t)(tok0 + sx_tok) * D_DIM + k0 + sx_kq * 4);
#pragma unroll
        for (int r = 0; r < 5; ++r) {
            int idx = tid + 256 * r;         // 0..1279
            int col = idx >> 3;              // 0..159
            int kq  = idx & 7;
            const float* p;
            if (col < 128)      p = gen_w  + (size_t)col * D_DIM;
            else if (col < 136) p = sel_w  + (size_t)(col-128) * D_DIM;
            else if (col < 140) p = comb_w + (size_t)(col-136) * D_DIM;
            else                p = gen_w;   // pad cols: junk, never read
            wr[r] = *(const float4*)(p + k0 + kq * 4);
        }
    };
    auto write_step = [&]() {
        xs[sx_kq*4+0][sx_tok] = xr.x; xs[sx_kq*4+1][sx_tok] = xr.y;
        xs[sx_kq*4+2][sx_tok] = xr.z; xs[sx_kq*4+3][sx_tok] = xr.w;
#pragma unroll
        for (int r = 0; r < 5; ++r) {
            int idx = tid + 256 * r;
            int col = idx >> 3;
            int kq  = idx & 7;
            wlds[kq*4+0][col] = wr[r].x; wlds[kq*4+1][col] = wr[r].y;
            wlds[kq*4+2][col] = wr[r].z; wlds[kq*4+3][col] = wr[r].w;
        }
    };

    load_step(0);
    write_step();

    for (int step = 0; step < 32; ++step) {
        __syncthreads();   // staged data visible
        int k0n = (step < 31 ? step + 1 : 31) * P1_KC;
        load_step(k0n);    // prefetch next under compute
#pragma unroll 4
        for (int kk = 0; kk < P1_KC; ++kk) {
            const float4 xv = *(const float4*)&xs[kk][tg*4];
            float wv[5];
#pragma unroll
            for (int cc = 0; cc < 5; ++cc) wv[cc] = wlds[kk][cg*5+cc];
#pragma unroll
            for (int cc = 0; cc < 5; ++cc) {
                acc[0][cc] += xv.x * wv[cc];
                acc[1][cc] += xv.y * wv[cc];
                acc[2][cc] += xv.z * wv[cc];
                acc[3][cc] += xv.w * wv[cc];
            }
        }
        __syncthreads();   // all reads done before overwrite
        write_step();
    }

#pragma unroll
    for (int r = 0; r < 4; ++r)
#pragma unroll
        for (int cc = 0; cc < 5; ++cc) outs[tg*4+r][cg*5+cc] = acc[r][cc];
    __syncthreads();

    // -------- epilogue: probs, comb, C, t, stores (unchanged) --------
    const int ig  = tid >> 5;   // 0..7 -> 4 pattern rows each
    const int ltk = tid & 31;
    const size_t token = (size_t)tok0 + ltk;

    float p[8];
    {
        float lg[8];
#pragma unroll
        for (int mI = 0; mI < 8; ++mI) lg[mI] = outs[ltk][128+mI];
        float mx = lg[0];
#pragma unroll
        for (int mI = 1; mI < 8; ++mI) mx = fmaxf(mx, lg[mI]);
        float sum = 0.f;
#pragma unroll
        for (int mI = 0; mI < 8; ++mI) { p[mI] = __expf(lg[mI]-mx); sum += p[mI]; }
        float inv = 1.0f / sum;
#pragma unroll
        for (int mI = 0; mI < 8; ++mI) p[mI] *= inv;
    }

    if (ig == 0) {
#pragma unroll
        for (int hh = 0; hh < 4; ++hh) combo[token*4+hh] = outs[ltk][136+hh];
    }

#pragma unroll 1
    for (int r = 0; r < 4; ++r) {
        const int i = ig*4 + r;
        float crow[32];
#pragma unroll
        for (int j = 0; j < 32; ++j) crow[j] = 0.f;
#pragma unroll
        for (int mI = 0; mI < 8; ++mI) {
            const float4* Tp = (const float4*)(templates + ((size_t)mI*32 + i)*32);
            const float pm = p[mI];
#pragma unroll
            for (int j4 = 0; j4 < 8; ++j4) {
                float4 t4 = Tp[j4];
                crow[j4*4+0] += pm*t4.x; crow[j4*4+1] += pm*t4.y;
                crow[j4*4+2] += pm*t4.z; crow[j4*4+3] += pm*t4.w;
            }
        }
#pragma unroll
        for (int hh = 0; hh < 4; ++hh) {
            float s = 0.f;
#pragma unroll
            for (int j4 = 0; j4 < 8; ++j4) {
                float4 f4 = *(const float4*)&outs[ltk][hh*32 + j4*4];
                s += crow[j4*4+0]*f4.x + crow[j4*4+1]*f4.y
                   + crow[j4*4+2]*f4.z + crow[j4*4+3]*f4.w;
            }
            tv[token*128 + hh*32 + i] = s;
        }
    }

#pragma unroll
    for (int pp = 0; pp < 4; ++pp) {
        int tk = (tid >> 5) + 8*pp;
        int j4 = tid & 31;
        float4 v = *(const float4*)&outs[tk][j4*4];
        *(float4*)&kf[((size_t)tok0 + tk)*128 + j4*4] = v;
    }
}

// ============================ Phase 2a: stats ============================
// Per (h,b,row): final max m and coef = comb/Z. 8-row tiles, paired (t, 255-t)
// per WG for uniform work. Wave=head; lane: qg(0..3) x sg(0..15); 2 rows/lane
// (treg = 64 VGPR -> stays resident).
__global__ __launch_bounds__(256) void lap_p2stats(
    const float* __restrict__ kf, const float* __restrict__ tv,
    const float* __restrict__ combo,
    float* __restrict__ m_arr, float* __restrict__ cf_arr)
{
    const int wg = blockIdx.x;       // 512
    const int b = wg & 3;
    const int w = wg >> 2;           // 0..127
    const int tid = threadIdx.x;
    const int h  = tid >> 6;
    const int l  = tid & 63;
    const int qg = l >> 4;
    const int sg = l & 15;
    const float* kfb = kf + (size_t)b * S_LEN * 128;

    for (int tsel = 0; tsel < 2; ++tsel) {
        const int t = tsel ? (255 - w) : w;
        const int q0 = t * 8;

        int row[2];
        float4 treg[2][8];
        float m[2], Z[2];
#pragma unroll
        for (int r = 0; r < 2; ++r) {
            row[r] = q0 + qg*2 + r;
            const float4* tp = (const float4*)(tv + ((size_t)(b*S_LEN) + row[r])*128 + h*32);
#pragma unroll
            for (int j4 = 0; j4 < 8; ++j4) treg[r][j4] = tp[j4];
            m[r] = -1e30f; Z[r] = 0.f;
        }

        const int nIt = (q0 + 23) >> 4;
        for (int it = 0; it < nIt; ++it) {
            const int s = it*16 + sg;
            const float4* kp = (const float4*)(kfb + (size_t)s*128 + h*32);
            float4 kreg[8];
#pragma unroll
            for (int j4 = 0; j4 < 8; ++j4) kreg[j4] = kp[j4];
#pragma unroll
            for (int r = 0; r < 2; ++r) {
                float sco = 0.f;
#pragma unroll
                for (int j4 = 0; j4 < 8; ++j4) {
                    sco += kreg[j4].x*treg[r][j4].x + kreg[j4].y*treg[r][j4].y
                         + kreg[j4].z*treg[r][j4].z + kreg[j4].w*treg[r][j4].w;
                }
                if (s <= row[r]) {
                    if (sco > m[r]) { Z[r] = Z[r]*__expf(m[r]-sco) + 1.0f; m[r] = sco; }
                    else            { Z[r] += __expf(sco - m[r]); }
                }
            }
        }

        // butterfly over the 16 key-slot lanes
#pragma unroll
        for (int r = 0; r < 2; ++r) {
#pragma unroll
            for (int wd = 1; wd < 16; wd <<= 1) {
                float mo = __shfl_xor(m[r], wd, 64);
                float Zo = __shfl_xor(Z[r], wd, 64);
                float mn = fmaxf(m[r], mo);
                Z[r] = Z[r]*__expf(m[r]-mn) + Zo*__expf(mo-mn);
                m[r] = mn;
            }
        }

        if (sg == 0) {
#pragma unroll
            for (int r = 0; r < 2; ++r) {
                size_t idx = ((size_t)(b*S_LEN) + row[r])*4 + h;
                m_arr[idx]  = m[r];
                cf_arr[idx] = combo[idx] / Z[r];
            }
        }
    }
}

// ============================ Phase 2b: write ============================
// Grid over causal chunks (b, 8q-tile, 128-key chunk); rect grid + early exit.
// Uniform work per WG -> full occupancy, no imbalance.
__global__ __launch_bounds__(256) void lap_p2write(
    const float* __restrict__ kf, const float* __restrict__ tv,
    const float* __restrict__ m_arr, const float* __restrict__ cf_arr,
    float* __restrict__ out)
{
    __shared__ float sc[4][8][132];

    const int wg = blockIdx.x;
    const int b = wg & 3;
    const int rest = wg >> 2;
    const int t = rest & 255;        // 8-row tile
    const int ck = rest >> 8;        // key chunk 0..16
    const int q0 = t * 8;
    const int ncha = (q0 + 8 + 127) >> 7;
    if (ck >= ncha) return;
    const int s0 = ck * 128;

    const int tid = threadIdx.x;
    const int h  = tid >> 6;
    const int l  = tid & 63;
    const int qg = l >> 4;
    const int sg = l & 15;
    const float* kfb = kf + (size_t)b * S_LEN * 128;

    int row[2];
    float4 treg[2][8];
    float mm[2], cf[2];
#pragma unroll
    for (int r = 0; r < 2; ++r) {
        row[r] = q0 + qg*2 + r;
        const float4* tp = (const float4*)(tv + ((size_t)(b*S_LEN) + row[r])*128 + h*32);
#pragma unroll
        for (int j4 = 0; j4 < 8; ++j4) treg[r][j4] = tp[j4];
        size_t idx = ((size_t)(b*S_LEN) + row[r])*4 + h;
        mm[r] = m_arr[idx];
        cf[r] = cf_arr[idx];
    }

#pragma unroll 2
    for (int it2 = 0; it2 < 8; ++it2) {
        const int s = s0 + it2*16 + sg;
        const float4* kp = (const float4*)(kfb + (size_t)s*128 + h*32);
        float4 kreg[8];
#pragma unroll
        for (int j4 = 0; j4 < 8; ++j4) kreg[j4] = kp[j4];
#pragma unroll
        for (int r = 0; r < 2; ++r) {
            float sco = 0.f;
#pragma unroll
            for (int j4 = 0; j4 < 8; ++j4) {
                sco += kreg[j4].x*treg[r][j4].x + kreg[j4].y*treg[r][j4].y
                     + kreg[j4].z*treg[r][j4].z + kreg[j4].w*treg[r][j4].w;
            }
            float val = (s <= row[r]) ? __expf(sco - mm[r]) * cf[r] : 0.0f;
            sc[h][qg*2+r][it2*16+sg] = val;
        }
    }
    __syncthreads();

    // head combine: 8 rows x 128 keys, all 256 threads, float4 out
    const int qq = tid >> 5;    // 0..7
    const int sp = tid & 31;    // float4 over 128 keys
    float4 a;
    a.x = a.y = a.z = a.w = 0.f;
#pragma unroll
    for (int hh = 0; hh < 4; ++hh) {
        const float4 v = *(const float4*)&sc[hh][qq][sp*4];
        a.x += v.x; a.y += v.y; a.z += v.z; a.w += v.w;
    }
    *(float4*)&out[((size_t)(b*S_LEN) + q0 + qq)*S_LEN + s0 + sp*4] = a;
}

// ============================ Phase 2c: zero-fill ============================
__global__ __launch_bounds__(256) void lap_p2zero(float* __restrict__ out)
{
    const int wg = blockIdx.x;      // 1024
    const int b = wg & 3;
    const int t = wg >> 2;          // 0..255
    const int q0 = t * 8;
    const int zs = ((q0 + 8 + 127) >> 7) << 7;   // chunk-covered end
    if (zs >= S_LEN) return;
    const int tid = threadIdx.x;
    float4 z4; z4.x = z4.y = z4.z = z4.w = 0.f;
#pragma unroll 1
    for (int rr = 0; rr < 8; ++rr) {
        float* rowp = out + ((size_t)(b*S_LEN) + q0 + rr) * S_LEN;
        for (int s = zs + tid*4; s < S_LEN; s += 1024)
            *(float4*)&rowp[s] = z4;
    }
}

// ============================ launch ============================
extern "C" void kernel_launch(void* const* d_in, const int* in_sizes, int n_in,
                              void* d_out, int out_size, void* d_ws, size_t ws_size,
                              hipStream_t stream) {
    const float* x         = (const float*)d_in[0];
    const float* gen_w     = (const float*)d_in[1];
    const float* gen_b     = (const float*)d_in[2];
    const float* sel_w     = (const float*)d_in[3];
    const float* sel_b     = (const float*)d_in[4];
    const float* templates = (const float*)d_in[5];
    const float* comb_w    = (const float*)d_in[6];
    const float* comb_b    = (const float*)d_in[7];

    float* ws = (float*)d_ws;
    float* kf    = ws;                     // [8192][128] feats
    float* tv    = ws + 1048576;           // [8192][128] t = C @ feat
    float* combo = ws + 2097152;           // [8192][4]   comb weights
    float* m_arr = ws + 2097152 + 32768;   // [8192][4]   row max per head
    float* cf_arr= ws + 2097152 + 65536;   // [8192][4]   comb/Z per head

    lap_phase1<<<256, 256, 0, stream>>>(x, gen_w, gen_b, sel_w, sel_b,
                                        templates, comb_w, comb_b,
                                        kf, tv, combo);
    lap_p2stats<<<512, 256, 0, stream>>>(kf, tv, combo, m_arr, cf_arr);
    lap_p2write<<<17408, 256, 0, stream>>>(kf, tv, m_arr, cf_arr, (float*)d_out);
    lap_p2zero<<<1024, 256, 0, stream>>>((float*)d_out);
}

// Round 5
// 279.045 us; speedup vs baseline: 2.3664x; 2.3664x over previous
//
#include <hip/hip_runtime.h>

#define S_LEN 2048
#define D_DIM 1024

typedef short bf16x8 __attribute__((ext_vector_type(8)));   // 8 bf16 (4 VGPRs)
typedef float f32x4  __attribute__((ext_vector_type(4)));   // MFMA acc
typedef unsigned short us8 __attribute__((ext_vector_type(8)));

__device__ __forceinline__ unsigned short f2bf(float f) {   // RNE f32->bf16
    unsigned int u = __builtin_bit_cast(unsigned int, f);
    u += 0x7FFFu + ((u >> 16) & 1u);
    return (unsigned short)(u >> 16);
}
__device__ __forceinline__ float bf2f(unsigned short h) {
    unsigned int u = ((unsigned int)h) << 16;
    return __builtin_bit_cast(float, u);
}

// ============================ Phase 1 ============================
// [16 tok x 1024] x [1024 x 160] fp32 GEMM per WG (512 WGs, 128 thr:
// 32 colgroups x 4 tokgroups, 4tok x 5col register tile). Epilogue:
// softmax(sel), C = sum_m p_m T_m, t = C@feat; emit kf/tv as SPLIT-BF16
// (hi+lo) in MFMA-fragment-friendly [h*4+b][s][32] layout + combo f32.
#define P1_TOK 16
#define P1_KC 32
#define P1_XSTR 18
#define P1_OSTR 164

__global__ __launch_bounds__(128) void lap_phase1(
    const float* __restrict__ x,
    const float* __restrict__ gen_w, const float* __restrict__ gen_b,
    const float* __restrict__ sel_w, const float* __restrict__ sel_b,
    const float* __restrict__ templates,
    const float* __restrict__ comb_w, const float* __restrict__ comb_b,
    unsigned short* __restrict__ kf_hi, unsigned short* __restrict__ kf_lo,
    unsigned short* __restrict__ tv_hi, unsigned short* __restrict__ tv_lo,
    float* __restrict__ combo)
{
    __shared__ float xs[P1_KC][P1_XSTR];     // [k][tok]
    __shared__ float wlds[P1_KC][P1_OSTR];   // [k][col]
    __shared__ float outs[P1_TOK][P1_OSTR];

    const int tid  = threadIdx.x;            // 128
    const int tok0 = blockIdx.x * P1_TOK;
    const int bI    = tok0 >> 11;
    const int srow0 = tok0 & 2047;
    const int cg = tid & 31;                 // cols cg*5..+4
    const int tg = tid >> 5;                 // toks tg*4..+3

    float bias5[5];
#pragma unroll
    for (int cc = 0; cc < 5; ++cc) {
        int col = cg * 5 + cc;
        if (col < 128)      bias5[cc] = gen_b[col];
        else if (col < 136) bias5[cc] = sel_b[col-128];
        else if (col < 140) bias5[cc] = comb_b[col-136];
        else                bias5[cc] = 0.0f;
    }
    float acc[4][5];
#pragma unroll
    for (int r = 0; r < 4; ++r)
#pragma unroll
        for (int cc = 0; cc < 5; ++cc) acc[r][cc] = bias5[cc];

    const int sx_tok = tid >> 3;   // 0..15
    const int sx_kq  = tid & 7;    // 0..7
    float4 xr;
    float4 wr[10];

    auto load_step = [&](int k0) {
        xr = *(const float4*)(x + (size_t)(tok0 + sx_tok) * D_DIM + k0 + sx_kq * 4);
#pragma unroll
        for (int r = 0; r < 10; ++r) {
            int idx = tid + 128 * r;         // 0..1279
            int col = idx >> 3;              // 0..159
            int kq  = idx & 7;
            const float* p;
            if (col < 128)      p = gen_w  + (size_t)col * D_DIM;
            else if (col < 136) p = sel_w  + (size_t)(col-128) * D_DIM;
            else if (col < 140) p = comb_w + (size_t)(col-136) * D_DIM;
            else                p = gen_w;   // pad cols: junk, never read
            wr[r] = *(const float4*)(p + k0 + kq * 4);
        }
    };
    auto write_step = [&]() {
        xs[sx_kq*4+0][sx_tok] = xr.x; xs[sx_kq*4+1][sx_tok] = xr.y;
        xs[sx_kq*4+2][sx_tok] = xr.z; xs[sx_kq*4+3][sx_tok] = xr.w;
#pragma unroll
        for (int r = 0; r < 10; ++r) {
            int idx = tid + 128 * r;
            int col = idx >> 3;
            int kq  = idx & 7;
            wlds[kq*4+0][col] = wr[r].x; wlds[kq*4+1][col] = wr[r].y;
            wlds[kq*4+2][col] = wr[r].z; wlds[kq*4+3][col] = wr[r].w;
        }
    };

    load_step(0);
    write_step();

    for (int step = 0; step < 32; ++step) {
        __syncthreads();
        int k0n = (step < 31 ? step + 1 : 31) * P1_KC;
        load_step(k0n);
#pragma unroll 4
        for (int kk = 0; kk < P1_KC; ++kk) {
            const float4 xv = *(const float4*)&xs[kk][tg*4];
            float wv[5];
#pragma unroll
            for (int cc = 0; cc < 5; ++cc) wv[cc] = wlds[kk][cg*5+cc];
#pragma unroll
            for (int cc = 0; cc < 5; ++cc) {
                acc[0][cc] += xv.x * wv[cc];
                acc[1][cc] += xv.y * wv[cc];
                acc[2][cc] += xv.z * wv[cc];
                acc[3][cc] += xv.w * wv[cc];
            }
        }
        __syncthreads();
        write_step();
    }

#pragma unroll
    for (int r = 0; r < 4; ++r)
#pragma unroll
        for (int cc = 0; cc < 5; ++cc) outs[tg*4+r][cg*5+cc] = acc[r][cc];
    __syncthreads();

    // -------- epilogue --------
    const int ltk = tid & 15;      // token in tile
    const int ig  = tid >> 4;      // 0..7 -> pattern rows ig*4..+3
    const int srow = srow0 + ltk;

    float p[8];
    {
        float lg[8];
#pragma unroll
        for (int mI = 0; mI < 8; ++mI) lg[mI] = outs[ltk][128+mI];
        float mx = lg[0];
#pragma unroll
        for (int mI = 1; mI < 8; ++mI) mx = fmaxf(mx, lg[mI]);
        float sum = 0.f;
#pragma unroll
        for (int mI = 0; mI < 8; ++mI) { p[mI] = __expf(lg[mI]-mx); sum += p[mI]; }
        float inv = 1.0f / sum;
#pragma unroll
        for (int mI = 0; mI < 8; ++mI) p[mI] *= inv;
    }

    if (tid < 64) {
        int hh = tid >> 4, tk = tid & 15;
        combo[(size_t)(hh*4+bI)*S_LEN + srow0 + tk] = outs[tk][136+hh];
    }

#pragma unroll 1
    for (int rr = 0; rr < 4; ++rr) {
        const int i = ig*4 + rr;
        float crow[32];
#pragma unroll
        for (int j = 0; j < 32; ++j) crow[j] = 0.f;
#pragma unroll
        for (int mI = 0; mI < 8; ++mI) {
            const float4* Tp = (const float4*)(templates + ((size_t)mI*32 + i)*32);
            const float pm = p[mI];
#pragma unroll
            for (int j4 = 0; j4 < 8; ++j4) {
                float4 t4 = Tp[j4];
                crow[j4*4+0] += pm*t4.x; crow[j4*4+1] += pm*t4.y;
                crow[j4*4+2] += pm*t4.z; crow[j4*4+3] += pm*t4.w;
            }
        }
#pragma unroll
        for (int hh = 0; hh < 4; ++hh) {
            float s = 0.f;
#pragma unroll
            for (int j4 = 0; j4 < 8; ++j4) {
                float4 f4 = *(const float4*)&outs[ltk][hh*32 + j4*4];
                s += crow[j4*4+0]*f4.x + crow[j4*4+1]*f4.y
                   + crow[j4*4+2]*f4.z + crow[j4*4+3]*f4.w;
            }
            unsigned short hi_ = f2bf(s);
            size_t off = ((size_t)(hh*4+bI)*S_LEN + srow)*32 + i;
            tv_hi[off] = hi_;
            tv_lo[off] = f2bf(s - bf2f(hi_));
        }
    }

    // kf split-bf16 store: 16 tok x 128 vals; thread: 2 blocks of 8
    {
        const int tok = tid >> 3;
        const int jb  = tid & 7;
        const int srw = srow0 + tok;
#pragma unroll
        for (int half = 0; half < 2; ++half) {
            int j0 = jb*16 + half*8;
            int hh = j0 >> 5;
            int ji = j0 & 31;
            us8 vh, vl;
#pragma unroll
            for (int e = 0; e < 8; ++e) {
                float f = outs[tok][j0+e];
                unsigned short h_ = f2bf(f);
                vh[e] = h_;
                vl[e] = f2bf(f - bf2f(h_));
            }
            size_t off = ((size_t)(hh*4+bI)*S_LEN + srw)*32 + ji;
            *(us8*)(kf_hi + off) = vh;
            *(us8*)(kf_lo + off) = vl;
        }
    }
}

// ============================ Phase 2a: stats (MFMA) ============================
// WG: (b, 32-q-tile), 4 waves = 4 heads. Scores via split-bf16 MFMA
// (hi*hi + hi*lo + lo*hi), flash-style online (m,Z) per row, butterfly
// over the 16 col-lanes. C-layout: col=lane&15, row=(lane>>4)*4+reg.
__global__ __launch_bounds__(256) void lap_p2stats(
    const unsigned short* __restrict__ kf_hi, const unsigned short* __restrict__ kf_lo,
    const unsigned short* __restrict__ tv_hi, const unsigned short* __restrict__ tv_lo,
    const float* __restrict__ combo,
    float* __restrict__ m_arr, float* __restrict__ cf_arr)
{
    const int wg = blockIdx.x;           // 256
    const int b  = wg & 3;
    const int qt = 63 - (wg >> 2);       // heavy-first (LPT)
    const int q0 = qt * 32;
    const int tid = threadIdx.x;
    const int h  = tid >> 6;
    const int l  = tid & 63;
    const int lc = l & 15;               // frag row/col index
    const int lk = l >> 4;               // k-slice
    const size_t hb = (size_t)(h*4+b) * S_LEN;

    bf16x8 Ah[2], Al[2];
#pragma unroll
    for (int qb = 0; qb < 2; ++qb) {
        size_t off = (hb + q0 + qb*16 + lc)*32 + lk*8;
        Ah[qb] = *(const bf16x8*)(tv_hi + off);
        Al[qb] = *(const bf16x8*)(tv_lo + off);
    }

    float m[2][4], Z[2][4];
#pragma unroll
    for (int qb = 0; qb < 2; ++qb)
#pragma unroll
        for (int r = 0; r < 4; ++r) { m[qb][r] = -1e30f; Z[qb][r] = 0.f; }

    const int nkt = ((q0 + 31) >> 6) + 1;
    for (int kt = 0; kt < nkt; ++kt) {
        const int k0 = kt * 64;
        bf16x8 Bh[4], Bl[4];
#pragma unroll
        for (int kb = 0; kb < 4; ++kb) {
            size_t off = (hb + k0 + kb*16 + lc)*32 + lk*8;
            Bh[kb] = *(const bf16x8*)(kf_hi + off);
            Bl[kb] = *(const bf16x8*)(kf_lo + off);
        }
        const bool maskT = (k0 + 63 > q0);
#pragma unroll
        for (int qb = 0; qb < 2; ++qb) {
            f32x4 accv[4];
#pragma unroll
            for (int kb = 0; kb < 4; ++kb) {
                f32x4 a = {0.f, 0.f, 0.f, 0.f};
                a = __builtin_amdgcn_mfma_f32_16x16x32_bf16(Ah[qb], Bh[kb], a, 0, 0, 0);
                a = __builtin_amdgcn_mfma_f32_16x16x32_bf16(Ah[qb], Bl[kb], a, 0, 0, 0);
                a = __builtin_amdgcn_mfma_f32_16x16x32_bf16(Al[qb], Bh[kb], a, 0, 0, 0);
                accv[kb] = a;
            }
#pragma unroll
            for (int r = 0; r < 4; ++r) {
                const int row = q0 + qb*16 + lk*4 + r;
                float v[4];
#pragma unroll
                for (int kb = 0; kb < 4; ++kb) {
                    v[kb] = accv[kb][r];
                    if (maskT && (k0 + kb*16 + lc > row)) v[kb] = -1e30f;
                }
                float tmax = fmaxf(fmaxf(v[0], v[1]), fmaxf(v[2], v[3]));
                float mo = m[qb][r];
                float mn = fmaxf(mo, tmax);
                Z[qb][r] = Z[qb][r]*__expf(mo - mn)
                         + __expf(v[0]-mn) + __expf(v[1]-mn)
                         + __expf(v[2]-mn) + __expf(v[3]-mn);
                m[qb][r] = mn;
            }
        }
    }

    // reduce over the 16 col-lanes (bits 0..3)
#pragma unroll
    for (int qb = 0; qb < 2; ++qb)
#pragma unroll
        for (int r = 0; r < 4; ++r) {
#pragma unroll
            for (int w = 1; w < 16; w <<= 1) {
                float mo = __shfl_xor(m[qb][r], w, 64);
                float Zo = __shfl_xor(Z[qb][r], w, 64);
                float mn = fmaxf(m[qb][r], mo);
                Z[qb][r] = Z[qb][r]*__expf(m[qb][r]-mn) + Zo*__expf(mo-mn);
                m[qb][r] = mn;
            }
        }

    if (lc == 0) {
#pragma unroll
        for (int qb = 0; qb < 2; ++qb)
#pragma unroll
            for (int r = 0; r < 4; ++r) {
                int row = q0 + qb*16 + lk*4 + r;
                size_t idx = hb + row;
                m_arr[idx]  = m[qb][r];
                cf_arr[idx] = combo[idx] / Z[qb][r];
            }
    }
}

// ============================ Phase 2b: write (MFMA) ============================
// Grid (b, 32-q-tile, 128-key chunk), uniform work. Recompute score tiles via
// MFMA, val = exp(s-m)*cf, LDS head-combine, coalesced float4 out.
__global__ __launch_bounds__(256) void lap_p2write(
    const unsigned short* __restrict__ kf_hi, const unsigned short* __restrict__ kf_lo,
    const unsigned short* __restrict__ tv_hi, const unsigned short* __restrict__ tv_lo,
    const float* __restrict__ m_arr, const float* __restrict__ cf_arr,
    float* __restrict__ out)
{
    __shared__ float sc[4][32][68];

    const int wg = blockIdx.x;           // 4096 = 4b x 64qt x 16ck
    const int b  = wg & 3;
    const int qt = (wg >> 2) & 63;
    const int ck = wg >> 8;
    const int q0 = qt * 32;
    const int ncha = (q0 + 32 + 127) >> 7;
    if (ck >= ncha) return;

    const int tid = threadIdx.x;
    const int h  = tid >> 6;
    const int l  = tid & 63;
    const int lc = l & 15;
    const int lk = l >> 4;
    const size_t hb = (size_t)(h*4+b) * S_LEN;

    bf16x8 Ah[2], Al[2];
    float mr[2][4], cf[2][4];
#pragma unroll
    for (int qb = 0; qb < 2; ++qb) {
        size_t off = (hb + q0 + qb*16 + lc)*32 + lk*8;
        Ah[qb] = *(const bf16x8*)(tv_hi + off);
        Al[qb] = *(const bf16x8*)(tv_lo + off);
#pragma unroll
        for (int r = 0; r < 4; ++r) {
            int row = q0 + qb*16 + lk*4 + r;
            mr[qb][r] = m_arr[hb + row];
            cf[qb][r] = cf_arr[hb + row];
        }
    }

#pragma unroll 1
    for (int i = 0; i < 2; ++i) {
        const int kt = ck*2 + i;
        const int k0 = kt * 64;
        if (k0 >= q0 + 32) break;        // invalid tail kt (zero kernel covers)

        bf16x8 Bh[4], Bl[4];
#pragma unroll
        for (int kb = 0; kb < 4; ++kb) {
            size_t off = (hb + k0 + kb*16 + lc)*32 + lk*8;
            Bh[kb] = *(const bf16x8*)(kf_hi + off);
            Bl[kb] = *(const bf16x8*)(kf_lo + off);
        }
        const bool maskT = (k0 + 63 > q0);
#pragma unroll
        for (int qb = 0; qb < 2; ++qb) {
#pragma unroll
            for (int kb = 0; kb < 4; ++kb) {
                f32x4 a = {0.f, 0.f, 0.f, 0.f};
                a = __builtin_amdgcn_mfma_f32_16x16x32_bf16(Ah[qb], Bh[kb], a, 0, 0, 0);
                a = __builtin_amdgcn_mfma_f32_16x16x32_bf16(Ah[qb], Bl[kb], a, 0, 0, 0);
                a = __builtin_amdgcn_mfma_f32_16x16x32_bf16(Al[qb], Bh[kb], a, 0, 0, 0);
#pragma unroll
                for (int r = 0; r < 4; ++r) {
                    const int row = q0 + qb*16 + lk*4 + r;
                    float sco = a[r];
                    if (maskT && (k0 + kb*16 + lc > row)) sco = -1e30f;
                    float val = __expf(sco - mr[qb][r]) * cf[qb][r];
                    sc[h][qb*16 + lk*4 + r][kb*16 + lc] = val;
                }
            }
        }
        __syncthreads();
#pragma unroll
        for (int t2 = 0; t2 < 2; ++t2) {
            int idx = tid + t2*256;      // 0..511
            int q  = idx >> 4;
            int c4 = idx & 15;
            float4 a4;
            const float4 v0 = *(const float4*)&sc[0][q][c4*4];
            const float4 v1 = *(const float4*)&sc[1][q][c4*4];
            const float4 v2 = *(const float4*)&sc[2][q][c4*4];
            const float4 v3 = *(const float4*)&sc[3][q][c4*4];
            a4.x = v0.x+v1.x+v2.x+v3.x;
            a4.y = v0.y+v1.y+v2.y+v3.y;
            a4.z = v0.z+v1.z+v2.z+v3.z;
            a4.w = v0.w+v1.w+v2.w+v3.w;
            *(float4*)&out[((size_t)(b*S_LEN) + q0 + q)*S_LEN + k0 + c4*4] = a4;
        }
        __syncthreads();
    }
}

// ============================ Phase 2c: zero-fill ============================
__global__ __launch_bounds__(256) void lap_p2zero(float* __restrict__ out)
{
    const int wg = blockIdx.x;      // 256
    const int b  = wg & 3;
    const int qt = wg >> 2;         // 0..63
    const int q0 = qt * 32;
    const int zs = ((q0 + 32 + 63) >> 6) << 6;   // first invalid 64-col tile
    if (zs >= S_LEN) return;
    const int tid = threadIdx.x;
    float4 z4; z4.x = z4.y = z4.z = z4.w = 0.f;
#pragma unroll 1
    for (int rr = 0; rr < 32; ++rr) {
        float* rowp = out + ((size_t)(b*S_LEN) + q0 + rr) * S_LEN;
        for (int s = zs + tid*4; s < S_LEN; s += 1024)
            *(float4*)&rowp[s] = z4;
    }
}

// ============================ launch ============================
extern "C" void kernel_launch(void* const* d_in, const int* in_sizes, int n_in,
                              void* d_out, int out_size, void* d_ws, size_t ws_size,
                              hipStream_t stream) {
    const float* x         = (const float*)d_in[0];
    const float* gen_w     = (const float*)d_in[1];
    const float* gen_b     = (const float*)d_in[2];
    const float* sel_w     = (const float*)d_in[3];
    const float* sel_b     = (const float*)d_in[4];
    const float* templates = (const float*)d_in[5];
    const float* comb_w    = (const float*)d_in[6];
    const float* comb_b    = (const float*)d_in[7];

    // workspace layout (8.375 MB, all [h*4+b][s][...] per-head-major)
    char* wsc = (char*)d_ws;
    unsigned short* kf_hi = (unsigned short*)(wsc);               // 16*2048*32 us = 2MB
    unsigned short* kf_lo = (unsigned short*)(wsc + 2097152);
    unsigned short* tv_hi = (unsigned short*)(wsc + 4194304);
    unsigned short* tv_lo = (unsigned short*)(wsc + 6291456);
    float* combo  = (float*)(wsc + 8388608);                      // [16][2048] f32
    float* m_arr  = combo + 32768;
    float* cf_arr = combo + 65536;

    lap_phase1<<<512, 128, 0, stream>>>(x, gen_w, gen_b, sel_w, sel_b,
                                        templates, comb_w, comb_b,
                                        kf_hi, kf_lo, tv_hi, tv_lo, combo);
    lap_p2stats<<<256, 256, 0, stream>>>(kf_hi, kf_lo, tv_hi, tv_lo,
                                         combo, m_arr, cf_arr);
    lap_p2write<<<4096, 256, 0, stream>>>(kf_hi, kf_lo, tv_hi, tv_lo,
                                          m_arr, cf_arr, (float*)d_out);
    lap_p2zero<<<256, 256, 0, stream>>>((float*)d_out);
}

// Round 9
// 220.719 us; speedup vs baseline: 2.9917x; 1.2643x over previous
//
#include <hip/hip_runtime.h>

#define S_LEN 2048
#define D_DIM 1024

typedef short bf16x8 __attribute__((ext_vector_type(8)));   // 8 bf16 (4 VGPRs)
typedef float f32x4  __attribute__((ext_vector_type(4)));   // MFMA acc
typedef unsigned short us8 __attribute__((ext_vector_type(8)));

__device__ __forceinline__ unsigned short f2bf(float f) {   // RNE f32->bf16
    unsigned int u = __builtin_bit_cast(unsigned int, f);
    u += 0x7FFFu + ((u >> 16) & 1u);
    return (unsigned short)(u >> 16);
}
__device__ __forceinline__ float bf2f(unsigned short h) {
    unsigned int u = ((unsigned int)h) << 16;
    return __builtin_bit_cast(float, u);
}

// ===================== prep: weights -> split-bf16 [144][1024] =====================
// rows 0-127 gen_w, 128-135 sel_w, 136-139 comb_w, 140-143 zero pad.
__global__ __launch_bounds__(256) void lap_prepw(
    const float* __restrict__ gen_w, const float* __restrict__ sel_w,
    const float* __restrict__ comb_w,
    unsigned short* __restrict__ w_hi, unsigned short* __restrict__ w_lo)
{
    const int idx = blockIdx.x * 256 + threadIdx.x;   // 0..18431
    const int e0 = idx * 8;
    const int row = e0 >> 10;
    const int k   = e0 & 1023;
    float v[8];
    const float* src = nullptr;
    if (row < 128)      src = gen_w  + (size_t)row * D_DIM + k;
    else if (row < 136) src = sel_w  + (size_t)(row-128) * D_DIM + k;
    else if (row < 140) src = comb_w + (size_t)(row-136) * D_DIM + k;
    if (src) {
        float4 a0 = ((const float4*)src)[0];
        float4 a1 = ((const float4*)src)[1];
        v[0]=a0.x; v[1]=a0.y; v[2]=a0.z; v[3]=a0.w;
        v[4]=a1.x; v[5]=a1.y; v[6]=a1.z; v[7]=a1.w;
    } else {
#pragma unroll
        for (int e = 0; e < 8; ++e) v[e] = 0.f;
    }
    us8 vh, vl;
#pragma unroll
    for (int e = 0; e < 8; ++e) {
        unsigned short h = f2bf(v[e]);
        vh[e] = h;
        vl[e] = f2bf(v[e] - bf2f(h));
    }
    *(us8*)(w_hi + e0) = vh;
    *(us8*)(w_lo + e0) = vl;
}

// ============================ Phase 1 (MFMA) ============================
// WG: 32 tokens x 144 cols, K=1024 in 16 steps of 64. x converted to split-bf16
// during LDS staging; weights pre-split by lap_prepw. 4 waves: (Mtile, Ngrp):
// wave owns 16 rows x {5,4} 16-col tiles; 3 MFMA passes (hh, hl, lh).
// Epilogue: softmax(sel), C=sum p_m T_m, t=C@feat, split-bf16 kf/tv stores.
#define P1_KC 64
#define P1_KP 72      // padded LDS k-stride (shorts)

__global__ __launch_bounds__(256) void lap_phase1(
    const float* __restrict__ x,
    const unsigned short* __restrict__ w_hi, const unsigned short* __restrict__ w_lo,
    const float* __restrict__ gen_b, const float* __restrict__ sel_b,
    const float* __restrict__ templates, const float* __restrict__ comb_b,
    unsigned short* __restrict__ kf_hi, unsigned short* __restrict__ kf_lo,
    unsigned short* __restrict__ tv_hi, unsigned short* __restrict__ tv_lo,
    float* __restrict__ combo)
{
    __shared__ __align__(16) short Ah[32][P1_KP];
    __shared__ __align__(16) short Al[32][P1_KP];
    __shared__ __align__(16) short Bh[144][P1_KP];
    __shared__ __align__(16) short Bl[144][P1_KP];
    __shared__ __align__(16) float outs[32][164];

    const int tid  = threadIdx.x;            // 256
    const int tok0 = blockIdx.x * 32;
    const int bI    = tok0 >> 11;
    const int srow0 = tok0 & 2047;

    // ---- staging mappings ----
    const int sa_tok = tid >> 3;             // 0..31
    const int sa_kq  = tid & 7;              // 0..7 (8 shorts each)
    float4 ax0, ax1;                         // A prefetch (f32)
    us8 bh[5], bl[5];                        // B prefetch

    auto load_step = [&](int k0) {
        const float* xp = x + (size_t)(tok0 + sa_tok) * D_DIM + k0 + sa_kq * 8;
        ax0 = ((const float4*)xp)[0];
        ax1 = ((const float4*)xp)[1];
#pragma unroll
        for (int r = 0; r < 5; ++r) {
            int idx = tid + 256 * r;         // 0..1279, valid < 1152
            if (idx < 1152) {
                int col = idx >> 3;
                int ko  = (idx & 7) * 8;
                bh[r] = *(const us8*)(w_hi + (size_t)col * D_DIM + k0 + ko);
                bl[r] = *(const us8*)(w_lo + (size_t)col * D_DIM + k0 + ko);
            }
        }
    };
    auto write_step = [&]() {
        us8 vh, vl;
        float f[8] = {ax0.x, ax0.y, ax0.z, ax0.w, ax1.x, ax1.y, ax1.z, ax1.w};
#pragma unroll
        for (int e = 0; e < 8; ++e) {
            unsigned short h = f2bf(f[e]);
            vh[e] = h;
            vl[e] = f2bf(f[e] - bf2f(h));
        }
        *(us8*)&Ah[sa_tok][sa_kq * 8] = vh;
        *(us8*)&Al[sa_tok][sa_kq * 8] = vl;
#pragma unroll
        for (int r = 0; r < 5; ++r) {
            int idx = tid + 256 * r;
            if (idx < 1152) {
                int col = idx >> 3;
                int ko  = (idx & 7) * 8;
                *(us8*)&Bh[col][ko] = bh[r];
                *(us8*)&Bl[col][ko] = bl[r];
            }
        }
    };

    // ---- wave tiling ----
    const int wid  = tid >> 6;
    const int lane = tid & 63;
    const int lc = lane & 15;
    const int lk = lane >> 4;
    const int Mtile = wid & 1;               // token half
    const int Ngrp  = wid >> 1;              // col group
    const int ntbase = Ngrp * 5;
    const int nnt    = Ngrp ? 4 : 5;         // tiles 0-4 / 5-8

    f32x4 acc[5];
#pragma unroll
    for (int t = 0; t < 5; ++t) {
        int col = (ntbase + t) * 16 + lc;
        float bv;
        if (col < 128)      bv = gen_b[col];
        else if (col < 136) bv = sel_b[col-128];
        else if (col < 140) bv = comb_b[col-136];
        else                bv = 0.0f;
        acc[t] = (f32x4){bv, bv, bv, bv};
    }

    load_step(0);
    write_step();

#pragma unroll 1
    for (int step = 0; step < 16; ++step) {
        __syncthreads();
        int k0n = (step < 15 ? step + 1 : 15) * P1_KC;
        load_step(k0n);
#pragma unroll
        for (int sub = 0; sub < 2; ++sub) {
            const int ko = sub * 32 + lk * 8;
            bf16x8 a_h = *(const bf16x8*)&Ah[Mtile*16 + lc][ko];
            bf16x8 a_l = *(const bf16x8*)&Al[Mtile*16 + lc][ko];
#pragma unroll
            for (int t = 0; t < 5; ++t) {
                if (t < nnt) {
                    const int brow = (ntbase + t) * 16 + lc;
                    bf16x8 b_h = *(const bf16x8*)&Bh[brow][ko];
                    bf16x8 b_l = *(const bf16x8*)&Bl[brow][ko];
                    acc[t] = __builtin_amdgcn_mfma_f32_16x16x32_bf16(a_h, b_h, acc[t], 0, 0, 0);
                    acc[t] = __builtin_amdgcn_mfma_f32_16x16x32_bf16(a_h, b_l, acc[t], 0, 0, 0);
                    acc[t] = __builtin_amdgcn_mfma_f32_16x16x32_bf16(a_l, b_h, acc[t], 0, 0, 0);
                }
            }
        }
        __syncthreads();
        write_step();
    }

    // acc -> outs  (D layout: row=(l>>4)*4+r, col=l&15)
#pragma unroll
    for (int t = 0; t < 5; ++t) {
        if (t < nnt) {
#pragma unroll
            for (int r = 0; r < 4; ++r)
                outs[Mtile*16 + lk*4 + r][(ntbase + t)*16 + lc] = acc[t][r];
        }
    }
    __syncthreads();

    // -------- epilogue (256 thr / 32 tokens) --------
    const int ltk = tid & 31;      // token in tile
    const int ig  = tid >> 5;      // 0..7 -> pattern rows ig*4..+3
    const int srow = srow0 + ltk;

    float p[8];
    {
        float lg[8];
#pragma unroll
        for (int mI = 0; mI < 8; ++mI) lg[mI] = outs[ltk][128+mI];
        float mx = lg[0];
#pragma unroll
        for (int mI = 1; mI < 8; ++mI) mx = fmaxf(mx, lg[mI]);
        float sum = 0.f;
#pragma unroll
        for (int mI = 0; mI < 8; ++mI) { p[mI] = __expf(lg[mI]-mx); sum += p[mI]; }
        float inv = 1.0f / sum;
#pragma unroll
        for (int mI = 0; mI < 8; ++mI) p[mI] *= inv;
    }

    if (tid < 128) {
        int hh = tid >> 5, tk = tid & 31;
        combo[(size_t)(hh*4+bI)*S_LEN + srow0 + tk] = outs[tk][136+hh];
    }

#pragma unroll 1
    for (int rr = 0; rr < 4; ++rr) {
        const int i = ig*4 + rr;
        float crow[32];
#pragma unroll
        for (int j = 0; j < 32; ++j) crow[j] = 0.f;
#pragma unroll
        for (int mI = 0; mI < 8; ++mI) {
            const float4* Tp = (const float4*)(templates + ((size_t)mI*32 + i)*32);
            const float pm = p[mI];
#pragma unroll
            for (int j4 = 0; j4 < 8; ++j4) {
                float4 t4 = Tp[j4];
                crow[j4*4+0] += pm*t4.x; crow[j4*4+1] += pm*t4.y;
                crow[j4*4+2] += pm*t4.z; crow[j4*4+3] += pm*t4.w;
            }
        }
#pragma unroll
        for (int hh = 0; hh < 4; ++hh) {
            float s = 0.f;
#pragma unroll
            for (int j4 = 0; j4 < 8; ++j4) {
                float4 f4 = *(const float4*)&outs[ltk][hh*32 + j4*4];
                s += crow[j4*4+0]*f4.x + crow[j4*4+1]*f4.y
                   + crow[j4*4+2]*f4.z + crow[j4*4+3]*f4.w;
            }
            unsigned short hi_ = f2bf(s);
            size_t off = ((size_t)(hh*4+bI)*S_LEN + srow)*32 + i;
            tv_hi[off] = hi_;
            tv_lo[off] = f2bf(s - bf2f(hi_));
        }
    }

    // kf split-bf16 store: 32 tok x 128 vals; thread: 2 blocks of 8
    {
        const int tok = tid >> 3;
        const int jb  = tid & 7;
        const int srw = srow0 + tok;
#pragma unroll
        for (int half = 0; half < 2; ++half) {
            int j0 = jb*16 + half*8;
            int hh = j0 >> 5;
            int ji = j0 & 31;
            us8 vh, vl;
#pragma unroll
            for (int e = 0; e < 8; ++e) {
                float f = outs[tok][j0+e];
                unsigned short h_ = f2bf(f);
                vh[e] = h_;
                vl[e] = f2bf(f - bf2f(h_));
            }
            size_t off = ((size_t)(hh*4+bI)*S_LEN + srw)*32 + ji;
            *(us8*)(kf_hi + off) = vh;
            *(us8*)(kf_lo + off) = vl;
        }
    }
}

// ============================ Phase 2a: stats (MFMA) ============================
__global__ __launch_bounds__(256) void lap_p2stats(
    const unsigned short* __restrict__ kf_hi, const unsigned short* __restrict__ kf_lo,
    const unsigned short* __restrict__ tv_hi, const unsigned short* __restrict__ tv_lo,
    const float* __restrict__ combo,
    float* __restrict__ m_arr, float* __restrict__ cf_arr)
{
    const int wg = blockIdx.x;           // 256
    const int b  = wg & 3;
    const int qt = 63 - (wg >> 2);       // heavy-first (LPT)
    const int q0 = qt * 32;
    const int tid = threadIdx.x;
    const int h  = tid >> 6;
    const int l  = tid & 63;
    const int lc = l & 15;               // frag row/col index
    const int lk = l >> 4;               // k-slice
    const size_t hb = (size_t)(h*4+b) * S_LEN;

    bf16x8 Ah[2], Al[2];
#pragma unroll
    for (int qb = 0; qb < 2; ++qb) {
        size_t off = (hb + q0 + qb*16 + lc)*32 + lk*8;
        Ah[qb] = *(const bf16x8*)(tv_hi + off);
        Al[qb] = *(const bf16x8*)(tv_lo + off);
    }

    float m[2][4], Z[2][4];
#pragma unroll
    for (int qb = 0; qb < 2; ++qb)
#pragma unroll
        for (int r = 0; r < 4; ++r) { m[qb][r] = -1e30f; Z[qb][r] = 0.f; }

    const int nkt = ((q0 + 31) >> 6) + 1;
    for (int kt = 0; kt < nkt; ++kt) {
        const int k0 = kt * 64;
        bf16x8 Bh[4], Bl[4];
#pragma unroll
        for (int kb = 0; kb < 4; ++kb) {
            size_t off = (hb + k0 + kb*16 + lc)*32 + lk*8;
            Bh[kb] = *(const bf16x8*)(kf_hi + off);
            Bl[kb] = *(const bf16x8*)(kf_lo + off);
        }
        const bool maskT = (k0 + 63 > q0);
#pragma unroll
        for (int qb = 0; qb < 2; ++qb) {
            f32x4 accv[4];
#pragma unroll
            for (int kb = 0; kb < 4; ++kb) {
                f32x4 a = {0.f, 0.f, 0.f, 0.f};
                a = __builtin_amdgcn_mfma_f32_16x16x32_bf16(Ah[qb], Bh[kb], a, 0, 0, 0);
                a = __builtin_amdgcn_mfma_f32_16x16x32_bf16(Ah[qb], Bl[kb], a, 0, 0, 0);
                a = __builtin_amdgcn_mfma_f32_16x16x32_bf16(Al[qb], Bh[kb], a, 0, 0, 0);
                accv[kb] = a;
            }
#pragma unroll
            for (int r = 0; r < 4; ++r) {
                const int row = q0 + qb*16 + lk*4 + r;
                float v[4];
#pragma unroll
                for (int kb = 0; kb < 4; ++kb) {
                    v[kb] = accv[kb][r];
                    if (maskT && (k0 + kb*16 + lc > row)) v[kb] = -1e30f;
                }
                float tmax = fmaxf(fmaxf(v[0], v[1]), fmaxf(v[2], v[3]));
                float mo = m[qb][r];
                float mn = fmaxf(mo, tmax);
                Z[qb][r] = Z[qb][r]*__expf(mo - mn)
                         + __expf(v[0]-mn) + __expf(v[1]-mn)
                         + __expf(v[2]-mn) + __expf(v[3]-mn);
                m[qb][r] = mn;
            }
        }
    }

#pragma unroll
    for (int qb = 0; qb < 2; ++qb)
#pragma unroll
        for (int r = 0; r < 4; ++r) {
#pragma unroll
            for (int w = 1; w < 16; w <<= 1) {
                float mo = __shfl_xor(m[qb][r], w, 64);
                float Zo = __shfl_xor(Z[qb][r], w, 64);
                float mn = fmaxf(m[qb][r], mo);
                Z[qb][r] = Z[qb][r]*__expf(m[qb][r]-mn) + Zo*__expf(mo-mn);
                m[qb][r] = mn;
            }
        }

    if (lc == 0) {
#pragma unroll
        for (int qb = 0; qb < 2; ++qb)
#pragma unroll
            for (int r = 0; r < 4; ++r) {
                int row = q0 + qb*16 + lk*4 + r;
                size_t idx = hb + row;
                m_arr[idx]  = m[qb][r];
                cf_arr[idx] = combo[idx] / Z[qb][r];
            }
    }
}

// ============================ Phase 2b: write (MFMA, zero-fold) ============================
__global__ __launch_bounds__(256) void lap_p2write(
    const unsigned short* __restrict__ kf_hi, const unsigned short* __restrict__ kf_lo,
    const unsigned short* __restrict__ tv_hi, const unsigned short* __restrict__ tv_lo,
    const float* __restrict__ m_arr, const float* __restrict__ cf_arr,
    float* __restrict__ out)
{
    __shared__ float sc[4][32][68];

    const int wg = blockIdx.x;           // 4096 = 4b x 64qt x 16ck
    const int b  = wg & 3;
    const int qt = (wg >> 2) & 63;
    const int ck = wg >> 8;
    const int q0 = qt * 32;

    const int tid = threadIdx.x;
    const int h  = tid >> 6;
    const int l  = tid & 63;
    const int lc = l & 15;
    const int lk = l >> 4;
    const size_t hb = (size_t)(h*4+b) * S_LEN;

    bf16x8 Ah[2], Al[2];
    float mr[2][4], cf[2][4];
    const bool anyValid = (ck * 128) < (q0 + 32);
    if (anyValid) {
#pragma unroll
        for (int qb = 0; qb < 2; ++qb) {
            size_t off = (hb + q0 + qb*16 + lc)*32 + lk*8;
            Ah[qb] = *(const bf16x8*)(tv_hi + off);
            Al[qb] = *(const bf16x8*)(tv_lo + off);
#pragma unroll
            for (int r = 0; r < 4; ++r) {
                int row = q0 + qb*16 + lk*4 + r;
                mr[qb][r] = m_arr[hb + row];
                cf[qb][r] = cf_arr[hb + row];
            }
        }
    }

#pragma unroll 1
    for (int i = 0; i < 2; ++i) {
        const int k0 = (ck*2 + i) * 64;
        if (k0 < q0 + 32) {
            bf16x8 Bh[4], Bl[4];
#pragma unroll
            for (int kb = 0; kb < 4; ++kb) {
                size_t off = (hb + k0 + kb*16 + lc)*32 + lk*8;
                Bh[kb] = *(const bf16x8*)(kf_hi + off);
                Bl[kb] = *(const bf16x8*)(kf_lo + off);
            }
            const bool maskT = (k0 + 63 > q0);
#pragma unroll
            for (int qb = 0; qb < 2; ++qb) {
#pragma unroll
                for (int kb = 0; kb < 4; ++kb) {
                    f32x4 a = {0.f, 0.f, 0.f, 0.f};
                    a = __builtin_amdgcn_mfma_f32_16x16x32_bf16(Ah[qb], Bh[kb], a, 0, 0, 0);
                    a = __builtin_amdgcn_mfma_f32_16x16x32_bf16(Ah[qb], Bl[kb], a, 0, 0, 0);
                    a = __builtin_amdgcn_mfma_f32_16x16x32_bf16(Al[qb], Bh[kb], a, 0, 0, 0);
#pragma unroll
                    for (int r = 0; r < 4; ++r) {
                        const int row = q0 + qb*16 + lk*4 + r;
                        float sco = a[r];
                        if (maskT && (k0 + kb*16 + lc > row)) sco = -1e30f;
                        float val = __expf(sco - mr[qb][r]) * cf[qb][r];
                        sc[h][qb*16 + lk*4 + r][kb*16 + lc] = val;
                    }
                }
            }
            __syncthreads();
#pragma unroll
            for (int t2 = 0; t2 < 2; ++t2) {
                int idx = tid + t2*256;      // 0..511
                int q  = idx >> 4;
                int c4 = idx & 15;
                float4 a4;
                const float4 v0 = *(const float4*)&sc[0][q][c4*4];
                const float4 v1 = *(const float4*)&sc[1][q][c4*4];
                const float4 v2 = *(const float4*)&sc[2][q][c4*4];
                const float4 v3 = *(const float4*)&sc[3][q][c4*4];
                a4.x = v0.x+v1.x+v2.x+v3.x;
                a4.y = v0.y+v1.y+v2.y+v3.y;
                a4.z = v0.z+v1.z+v2.z+v3.z;
                a4.w = v0.w+v1.w+v2.w+v3.w;
                *(float4*)&out[((size_t)(b*S_LEN) + q0 + q)*S_LEN + k0 + c4*4] = a4;
            }
            __syncthreads();
        } else {
            // fully-masked strip: zero-fill (replaces old lap_p2zero)
            float4 z4; z4.x = z4.y = z4.z = z4.w = 0.f;
#pragma unroll
            for (int t2 = 0; t2 < 2; ++t2) {
                int idx = tid + t2*256;
                int q  = idx >> 4;
                int c4 = idx & 15;
                *(float4*)&out[((size_t)(b*S_LEN) + q0 + q)*S_LEN + k0 + c4*4] = z4;
            }
        }
    }
}

// ============================ launch ============================
extern "C" void kernel_launch(void* const* d_in, const int* in_sizes, int n_in,
                              void* d_out, int out_size, void* d_ws, size_t ws_size,
                              hipStream_t stream) {
    const float* x         = (const float*)d_in[0];
    const float* gen_w     = (const float*)d_in[1];
    const float* gen_b     = (const float*)d_in[2];
    const float* sel_w     = (const float*)d_in[3];
    const float* sel_b     = (const float*)d_in[4];
    const float* templates = (const float*)d_in[5];
    const float* comb_w    = (const float*)d_in[6];
    const float* comb_b    = (const float*)d_in[7];

    // workspace layout, all [h*4+b][s][...] per-head-major for phase2
    char* wsc = (char*)d_ws;
    unsigned short* kf_hi = (unsigned short*)(wsc);               // 2 MB
    unsigned short* kf_lo = (unsigned short*)(wsc + 2097152);
    unsigned short* tv_hi = (unsigned short*)(wsc + 4194304);
    unsigned short* tv_lo = (unsigned short*)(wsc + 6291456);
    float* combo  = (float*)(wsc + 8388608);                      // [16][2048] f32
    float* m_arr  = combo + 32768;
    float* cf_arr = combo + 65536;
    unsigned short* w_hi = (unsigned short*)(wsc + 8388608 + 393216);   // [144][1024]
    unsigned short* w_lo = w_hi + 147456;

    lap_prepw<<<72, 256, 0, stream>>>(gen_w, sel_w, comb_w, w_hi, w_lo);
    lap_phase1<<<256, 256, 0, stream>>>(x, w_hi, w_lo, gen_b, sel_b,
                                        templates, comb_b,
                                        kf_hi, kf_lo, tv_hi, tv_lo, combo);
    lap_p2stats<<<256, 256, 0, stream>>>(kf_hi, kf_lo, tv_hi, tv_lo,
                                         combo, m_arr, cf_arr);
    lap_p2write<<<4096, 256, 0, stream>>>(kf_hi, kf_lo, tv_hi, tv_lo,
                                          m_arr, cf_arr, (float*)d_out);
}